// Round 11
// baseline (161.403 us; speedup 1.0000x reference)
//
#include <hip/hip_runtime.h>
#include <math.h>

// NeuralSplineCoupling: y[:, :3] = RQS(x[:, :3]; params = MLP([x[:,3:], c]))
//                       y[:, 3:] = x[:, 3:],  log_det = sum over 3 dims
// N = 500000, X_DIM=6, C_DIM=4, HID=128, KNOTS=16, SPLINE_DIM=47, OUT_DIM=141
//
// Round 11: TRANSPOSED MLP. Each layer computes h^T = W^T @ x^T (A = W^T,
// B = activations^T, samples on the MFMA N axis). Layer l's D output (lane:
// [feat lq*4+r][sample lm]) equals layer l+1's B operand (lane: [feat-slot
// lq*8+j][sample lm]) under the lane-invariant k-permutation
//   f(kc,lq,j) = (kc*2+(j>>2))*16 + lq*4 + (j&3)
// which is baked into the W2/W3 prepack. The D->B repack is in-lane relu+cvt
// register renaming -> ZERO LDS traffic for h1/h2 (round-10 post-mortem: the
// 32 b128/wave h round-trips + lgkm phase serialization were the shared-pipe
// ceiling). LDS is used only for the p handoff ([s][141] contiguous, 18
// ds_write_b64/wave) + spline reads (wave-uniform d -> non-divergent aligned
// vector loads) + shld. 40.4 KB -> 4 blocks/CU.

#define TILE 128
#define NT   256
#define HID  128
#define OUTD 141
#define SRS  152     // halves per sample in shp16 (304 B: 16B-aligned rows)
#define BND  5.0f
#define T1   0.5413248546f   // ln(e-1): softplus(T1) = 1

typedef __bf16 bf16;
typedef _Float16 f16;
typedef __attribute__((ext_vector_type(8))) __bf16 bf16x8;
typedef __attribute__((ext_vector_type(8))) _Float16 f16x8;
typedef __attribute__((ext_vector_type(4))) _Float16 f16x4;
typedef __attribute__((ext_vector_type(2))) _Float16 f16x2;
typedef __attribute__((ext_vector_type(4))) float f32x4;

#define W1P_ELEMS (8 * 64 * 8)        // 8 m-tiles (h1 feats), identity k (7 in feats)
#define W2P_ELEMS (8 * 4 * 64 * 8)    // 8 m-tiles x 4 kc, f-permuted k
#define W3P_ELEMS (9 * 4 * 64 * 8)    // 9 m-tiles x 4 kc, f-permuted k
#define NFRAG (512 + 2048 + 2304)     // 4864 fragments
#define B3P_OFF ((W1P_ELEMS + W2P_ELEMS + W3P_ELEMS) * 2)   // 77824 B (16-aligned)

// LDS: shp16 [0, 128*152*2=38912) dedicated | shld [38912, 40448)
#define SMEM_BYTES 40448

// One thread per 8-elem A-fragment (W^T in A-layout: A[m=lane&15][k=lq*8+j]).
__global__ void nsc_prepack(const float* __restrict__ W1, const float* __restrict__ W2,
                            const float* __restrict__ W3, const float* __restrict__ b3,
                            bf16* __restrict__ W1p, bf16* __restrict__ W2p,
                            bf16* __restrict__ W3p, float* __restrict__ b3p) {
    int f = blockIdx.x * 256 + threadIdx.x;
    int lane = f & 63, lm = lane & 15, lq = lane >> 4;
    if (f < 512) {                                   // W1^T: m = h1 feat, k = in feat (identity)
        int t = f >> 6;
        int m = t * 16 + lm;
        bf16x8 pk;
        #pragma unroll
        for (int j = 0; j < 8; ++j) {
            int k = lq * 8 + j;
            pk[j] = (k < 7) ? (bf16)W1[k * HID + m] : (bf16)0.f;
        }
        *(bf16x8*)&W1p[(size_t)f * 8] = pk;
    } else if (f < 512 + 2048) {                     // W2^T: m = h2 feat, k = h1 feat via f()
        int g2 = f - 512;
        int tk = g2 >> 6, t2 = tk >> 2, kc = tk & 3;
        int m = t2 * 16 + lm;
        bf16x8 pk;
        #pragma unroll
        for (int j = 0; j < 8; ++j) {
            int feat = ((kc * 2 + (j >> 2)) << 4) + (lq << 2) + (j & 3);
            pk[j] = (bf16)W2[feat * HID + m];
        }
        *(bf16x8*)&W2p[(size_t)g2 * 8] = pk;
    } else if (f < NFRAG) {                          // W3^T: m = p col, k = h2 feat via f()
        int g3 = f - 2560;
        int tk = g3 >> 6, t3 = tk >> 2, kc = tk & 3;
        int col = t3 * 16 + lm;
        bf16x8 pk;
        #pragma unroll
        for (int j = 0; j < 8; ++j) {
            int feat = ((kc * 2 + (j >> 2)) << 4) + (lq << 2) + (j & 3);
            pk[j] = (col < OUTD) ? (bf16)W3[feat * OUTD + col] : (bf16)0.f;
        }
        *(bf16x8*)&W3p[(size_t)g3 * 8] = pk;
    } else if (f < NFRAG + 144) {                    // b3 padded to 144
        int i = f - NFRAG;
        b3p[i] = (i < OUTD) ? b3[i] : 0.f;
    }
}

__global__ __launch_bounds__(NT, 4) void nsc_main(
    const float* __restrict__ x, const float* __restrict__ c,
    const bf16* __restrict__ W1p, const float* __restrict__ b1,
    const bf16* __restrict__ W2p, const float* __restrict__ b2,
    const bf16* __restrict__ W3p, const float* __restrict__ b3p,
    float* __restrict__ out_y, float* __restrict__ out_ld, int N)
{
    __shared__ __align__(16) char smem[SMEM_BYTES];
    f16*   shp16 = (f16*)smem;                  // [128][SRS], p at off = col (contiguous)
    float* shld  = (float*)(smem + 38912);      // [128][3]

    const int tid  = threadIdx.x;
    const int g0   = blockIdx.x * TILE;
    const int lane = tid & 63;
    const int wv   = tid >> 6;        // wave owns samples wv*32 .. wv*32+31 (2 sets x 16)
    const int lm   = lane & 15;
    const int lq   = lane >> 4;
    const int sbase = wv * 32;

    // ---- Inputs -> B1 fragments in registers (B[k=lq*8+j][n=sample lm]) ----
    bf16x8 inb[2];
    #pragma unroll
    for (int set = 0; set < 2; ++set) {
        int g = g0 + sbase + set * 16 + lm;
        float v[8] = {0.f, 0.f, 0.f, 0.f, 0.f, 0.f, 0.f, 0.f};
        if (lq == 0 && g < N) {
            v[0] = x[g * 6 + 3]; v[1] = x[g * 6 + 4]; v[2] = x[g * 6 + 5];
            v[3] = c[g * 4];     v[4] = c[g * 4 + 1];
            v[5] = c[g * 4 + 2]; v[6] = c[g * 4 + 3];
        }
        bf16x8 t;
        #pragma unroll
        for (int j = 0; j < 8; ++j) t[j] = (bf16)v[j];
        inb[set] = t;
    }

    // ---- Phase 1: h1^T = W1^T @ in^T + b1 (D: [feat t*16+lq*4+r][sample lm]) ----
    f32x4 acc1[2][8];
    {
        #pragma unroll
        for (int t = 0; t < 8; ++t) {
            f32x4 bb = *(const f32x4*)&b1[t * 16 + lq * 4];   // bias on M (feature) axis
            acc1[0][t] = bb; acc1[1][t] = bb;
        }
        #pragma unroll
        for (int t = 0; t < 8; ++t) {
            bf16x8 wf = *(const bf16x8*)&W1p[(size_t)(t * 64 + lane) * 8];
            acc1[0][t] = __builtin_amdgcn_mfma_f32_16x16x32_bf16(wf, inb[0], acc1[0][t], 0, 0, 0);
            acc1[1][t] = __builtin_amdgcn_mfma_f32_16x16x32_bf16(wf, inb[1], acc1[1][t], 0, 0, 0);
        }
    }
    // in-lane D->B repack: B2 slot (kc,j) <- relu(D1[t = kc*2+(j>>2)].r[j&3])
    bf16x8 h1B[2][4];
    #pragma unroll
    for (int set = 0; set < 2; ++set)
        #pragma unroll
        for (int kc = 0; kc < 4; ++kc) {
            bf16x8 hb;
            #pragma unroll
            for (int j = 0; j < 8; ++j)
                hb[j] = (bf16)fmaxf(acc1[set][kc * 2 + (j >> 2)][j & 3], 0.f);
            h1B[set][kc] = hb;
        }

    // ---- Phase 2: h2^T = W2^T @ h1^T + b2; tile-pairs, repack immediately ----
    bf16x8 h2B[2][4];
    #pragma unroll
    for (int tp = 0; tp < 4; ++tp) {
        f32x4 acc[2][2];
        #pragma unroll
        for (int dt = 0; dt < 2; ++dt) {
            f32x4 bb = *(const f32x4*)&b2[(tp * 2 + dt) * 16 + lq * 4];
            acc[0][dt] = bb; acc[1][dt] = bb;
        }
        #pragma unroll
        for (int kc = 0; kc < 4; ++kc)
            #pragma unroll
            for (int dt = 0; dt < 2; ++dt) {
                bf16x8 wf = *(const bf16x8*)&W2p[(size_t)(((tp * 2 + dt) * 4 + kc) * 64 + lane) * 8];
                acc[0][dt] = __builtin_amdgcn_mfma_f32_16x16x32_bf16(wf, h1B[0][kc], acc[0][dt], 0, 0, 0);
                acc[1][dt] = __builtin_amdgcn_mfma_f32_16x16x32_bf16(wf, h1B[1][kc], acc[1][dt], 0, 0, 0);
            }
        #pragma unroll
        for (int set = 0; set < 2; ++set) {
            bf16x8 hb;
            #pragma unroll
            for (int j = 0; j < 8; ++j)
                hb[j] = (bf16)fmaxf(acc[set][j >> 2][j & 3], 0.f);
            h2B[set][tp] = hb;      // kc-group of next GEMM == tp (f mapping)
        }
    }

    // ---- Phase 3: p^T = W3^T @ h2^T + b3; scatter straight to dedicated shp16 ----
    #pragma unroll
    for (int t3 = 0; t3 < 9; ++t3) {
        f32x4 acc[2];
        {
            f32x4 bb = *(const f32x4*)&b3p[t3 * 16 + lq * 4];
            acc[0] = bb; acc[1] = bb;
        }
        #pragma unroll
        for (int kc = 0; kc < 4; ++kc) {
            bf16x8 wf = *(const bf16x8*)&W3p[(size_t)((t3 * 4 + kc) * 64 + lane) * 8];
            acc[0] = __builtin_amdgcn_mfma_f32_16x16x32_bf16(wf, h2B[0][kc], acc[0], 0, 0, 0);
            acc[1] = __builtin_amdgcn_mfma_f32_16x16x32_bf16(wf, h2B[1][kc], acc[1], 0, 0, 0);
        }
        #pragma unroll
        for (int set = 0; set < 2; ++set) {
            int s = sbase + set * 16 + lm;
            f16x4 pk = (f16x4){(f16)acc[set][0], (f16)acc[set][1],
                               (f16)acc[set][2], (f16)acc[set][3]};
            int off = t3 * 16 + lq * 4;   // off = col; 8B-aligned b64 store
            if (t3 < 8) {
                *(f16x4*)&shp16[s * SRS + off] = pk;
            } else {
                if (lq < 3) *(f16x4*)&shp16[s * SRS + off] = pk;
                else        shp16[s * SRS + 140] = pk[0];   // col 140 only
            }
        }
    }
    __syncthreads();   // scatters visible to all waves

    // ---- Phase 4: spline; grp mapping makes d WAVE-UNIFORM (no divergence) ----
    for (int grp = wv; grp < 6; grp += 4) {
        const int d = grp >> 1;
        const int s = ((grp & 1) << 6) + lane;
        const int g = g0 + s;
        if (g < N) {
            const f16* pr = &shp16[s * SRS];
            float w_[16], h_[16], dl[15];
            if (d == 0) {               // p[0..46], base 16B-aligned
                f16x8 A0 = *(const f16x8*)&pr[0],  A1 = *(const f16x8*)&pr[8];
                f16x8 A2 = *(const f16x8*)&pr[16], A3 = *(const f16x8*)&pr[24];
                f16x8 A4 = *(const f16x8*)&pr[32], A5 = *(const f16x8*)&pr[40];
                #pragma unroll
                for (int i = 0; i < 8; ++i) {
                    w_[i] = (float)A0[i]; w_[8 + i] = (float)A1[i];
                    h_[i] = (float)A2[i]; h_[8 + i] = (float)A3[i];
                    dl[i] = (float)A4[i];
                }
                #pragma unroll
                for (int i = 0; i < 7; ++i) dl[8 + i] = (float)A5[i];
            } else if (d == 1) {        // p[47..93]
                float a47 = (float)pr[47];
                f16x8 A0 = *(const f16x8*)&pr[48], A1 = *(const f16x8*)&pr[56];
                f16x8 A2 = *(const f16x8*)&pr[64], A3 = *(const f16x8*)&pr[72];
                f16x8 A4 = *(const f16x8*)&pr[80], A5 = *(const f16x8*)&pr[88];
                w_[0] = a47;
                #pragma unroll
                for (int i = 0; i < 8; ++i) w_[1 + i] = (float)A0[i];    // 48..55
                #pragma unroll
                for (int i = 0; i < 7; ++i) w_[9 + i] = (float)A1[i];    // 56..62
                h_[0] = (float)A1[7];                                    // 63
                #pragma unroll
                for (int i = 0; i < 8; ++i) h_[1 + i] = (float)A2[i];    // 64..71
                #pragma unroll
                for (int i = 0; i < 7; ++i) h_[9 + i] = (float)A3[i];    // 72..78
                dl[0] = (float)A3[7];                                    // 79
                #pragma unroll
                for (int i = 0; i < 8; ++i) dl[1 + i] = (float)A4[i];    // 80..87
                #pragma unroll
                for (int i = 0; i < 6; ++i) dl[9 + i] = (float)A5[i];    // 88..93
            } else {                    // p[94..140]
                f16x2 B  = *(const f16x2*)&pr[94];
                f16x8 C0 = *(const f16x8*)&pr[96],  C1 = *(const f16x8*)&pr[104];
                f16x8 C2 = *(const f16x8*)&pr[112], C3 = *(const f16x8*)&pr[120];
                f16x8 C4 = *(const f16x8*)&pr[128], E  = *(const f16x8*)&pr[136];
                w_[0] = (float)B[0]; w_[1] = (float)B[1];                // 94,95
                #pragma unroll
                for (int i = 0; i < 8; ++i) w_[2 + i] = (float)C0[i];    // 96..103
                #pragma unroll
                for (int i = 0; i < 6; ++i) w_[10 + i] = (float)C1[i];   // 104..109
                h_[0] = (float)C1[6]; h_[1] = (float)C1[7];              // 110,111
                #pragma unroll
                for (int i = 0; i < 8; ++i) h_[2 + i] = (float)C2[i];    // 112..119
                #pragma unroll
                for (int i = 0; i < 6; ++i) h_[10 + i] = (float)C3[i];   // 120..125
                dl[0] = (float)C3[6]; dl[1] = (float)C3[7];              // 126,127
                #pragma unroll
                for (int i = 0; i < 8; ++i) dl[2 + i] = (float)C4[i];    // 128..135
                #pragma unroll
                for (int i = 0; i < 5; ++i) dl[10 + i] = (float)E[i];    // 136..140
            }

            // softmax without max-subtract: logits are O(1)
            float sw = 0.f, sh = 0.f;
            #pragma unroll
            for (int i = 0; i < 16; ++i) { w_[i] = __expf(w_[i]); sw += w_[i]; }
            #pragma unroll
            for (int i = 0; i < 16; ++i) { h_[i] = __expf(h_[i]); sh += h_[i]; }
            float cwn = 10.f * __builtin_amdgcn_rcpf(sw);
            float chn = 10.f * __builtin_amdgcn_rcpf(sh);
            #pragma unroll
            for (int i = 0; i < 16; ++i) { w_[i] *= cwn; h_[i] *= chn; }

            float xv = x[g * 6 + d];
            bool oob = (xv <= -BND) || (xv >= BND);
            float xm = oob ? -BND : xv;

            // bin scan; softplus deferred to the 2 selected derivs
            float cumx = -BND + w_[0], cumy = -BND + h_[0];
            float xk_b = -BND, yk_b = -BND;
            float wk = w_[0], hk = h_[0];
            float d0l = T1, d1l = dl[0];
            #pragma unroll
            for (int i = 1; i < 16; ++i) {
                bool ge = (xm >= cumx);
                if (ge) {
                    xk_b = cumx; yk_b = cumy;
                    wk = w_[i]; hk = h_[i];
                    d0l = dl[i - 1];
                    d1l = (i < 15) ? dl[i] : T1;
                }
                cumx += w_[i]; cumy += h_[i];
            }
            float d0 = (d0l > 15.f) ? d0l : __logf(1.f + __expf(d0l));
            float d1 = (d1l > 15.f) ? d1l : __logf(1.f + __expf(d1l));

            float rwk = __builtin_amdgcn_rcpf(wk);
            float sk = hk * rwk;
            float relx = (xm - xk_b) * rwk;
            relx = fminf(fmaxf(relx, 0.f), 1.f);
            float r1 = relx * (1.f - relx);
            float den = sk + (d1 + d0 - 2.f * sk) * r1;
            float iden = __builtin_amdgcn_rcpf(den);
            float num = hk * (sk * relx * relx + d0 * r1);
            float y = yk_b + num * iden;
            float omr = 1.f - relx;
            float arg = d1 * relx * relx + 2.f * sk * r1 + d0 * omr * omr;
            float ratio = sk * iden;
            float ld = __logf(ratio * ratio * arg);   // 2log(sk)+log(arg)-2log(den)
            if (oob) { y = xv; ld = 0.f; }

            out_y[g * 6 + d] = y;
            out_y[g * 6 + 3 + d] = x[g * 6 + 3 + d];  // upper pass-through (fp32)
            shld[s * 3 + d] = ld;
        }
    }
    __syncthreads();

    // ---- Phase 5: reduce log-det over the 3 dims ----
    if (tid < TILE) {
        int g = g0 + tid;
        if (g < N)
            out_ld[g] = shld[tid * 3] + shld[tid * 3 + 1] + shld[tid * 3 + 2];
    }
}

extern "C" void kernel_launch(void* const* d_in, const int* in_sizes, int n_in,
                              void* d_out, int out_size, void* d_ws, size_t ws_size,
                              hipStream_t stream) {
    const float* x  = (const float*)d_in[0];
    const float* c  = (const float*)d_in[1];
    const float* W1 = (const float*)d_in[2];
    const float* b1 = (const float*)d_in[3];
    const float* W2 = (const float*)d_in[4];
    const float* b2 = (const float*)d_in[5];
    const float* W3 = (const float*)d_in[6];
    const float* b3 = (const float*)d_in[7];

    const int N = in_sizes[0] / 6;              // 500000
    float* out_y  = (float*)d_out;
    float* out_ld = (float*)d_out + (size_t)N * 6;

    bf16*  W1p = (bf16*)d_ws;
    bf16*  W2p = W1p + W1P_ELEMS;
    bf16*  W3p = W2p + W2P_ELEMS;
    float* b3p = (float*)((char*)d_ws + B3P_OFF);

    int nthreads = NFRAG + 144;                 // 5008
    nsc_prepack<<<(nthreads + 255) / 256, 256, 0, stream>>>(W1, W2, W3, b3,
                                                            W1p, W2p, W3p, b3p);

    int nblocks = (N + TILE - 1) / TILE;        // 3907
    nsc_main<<<nblocks, NT, 0, stream>>>(x, c, W1p, b1, W2p, b2, W3p, b3p,
                                         out_y, out_ld, N);
}

// Round 12
// 153.730 us; speedup vs baseline: 1.0499x; 1.0499x over previous
//
#include <hip/hip_runtime.h>
#include <math.h>

// NeuralSplineCoupling: y[:, :3] = RQS(x[:, :3]; params = MLP([x[:,3:], c]))
//                       y[:, 3:] = x[:, 3:],  log_det = sum over 3 dims
// N = 500000, X_DIM=6, C_DIM=4, HID=128, KNOTS=16, SPLINE_DIM=47, OUT_DIM=141
//
// Round 12: r11 transposed MLP (register-chained layers, verified) + WEIGHTS
// STAGED IN LDS once per block. r7/r10/r11 all pinned at ~89 us with identical
// per-wave L2 weight traffic (76 KB/wave, 1.19 GB/launch) -> L2 broadcast of
// the 77 KB weight set was the wall. Staging cuts L2 weight traffic 4x
// (304 -> 77.8 KB/block); frag reads become ds_read_b128 (DS load ~3.7K
// cyc/block << VALU floor). LDS: [W3s 36864 | W1s+W2s 40960 (overlaid by shp16
// after a barrier) | shld] = 79360 B -> 2 blocks/CU, launch_bounds(256,2).
// d_ws reordered [W3p|W1p|W2p|b3p] so staging is one linear 77824 B copy.

#define TILE 128
#define NT   256
#define HID  128
#define OUTD 141
#define SRS  152     // halves per sample in shp16 (304 B rows)
#define BND  5.0f
#define T1   0.5413248546f   // ln(e-1): softplus(T1) = 1

typedef __bf16 bf16;
typedef _Float16 f16;
typedef __attribute__((ext_vector_type(8))) __bf16 bf16x8;
typedef __attribute__((ext_vector_type(8))) _Float16 f16x8;
typedef __attribute__((ext_vector_type(4))) _Float16 f16x4;
typedef __attribute__((ext_vector_type(2))) _Float16 f16x2;
typedef __attribute__((ext_vector_type(4))) float f32x4;

// fragment-index bases in the packed weight blob (fragment = 64 lanes x 16 B)
#define W3BASE 0         // 9 t3 x 4 kc = 36 tiles -> frags [0, 2304)
#define W1BASE 2304      // 8 tiles               -> frags [2304, 2816)
#define W2BASE 2816      // 8 m-tiles x 4 kc      -> frags [2816, 4864)
#define NFRAG  4864      // 77824 bytes total
#define B3P_OFF (NFRAG * 16)   // byte offset of b3p in d_ws

// LDS: wlds [0, 77824) = staged blob (same frag indexing as d_ws);
// shp16 [36864, 75776) overlays W1s+W2s (barrier-separated);
// shld [77824, 79360)
#define SMEM_BYTES 79360

// One thread per 8-elem A-fragment (W^T in A-layout: A[m=lane&15][k=lq*8+j]).
// k-permutation for W2/W3: feat = (kc*2+(j>>2))*16 + lq*4 + (j&3)  (f mapping,
// matches the in-lane D->B repack of the transposed chain — verified r11).
__global__ void nsc_prepack(const float* __restrict__ W1, const float* __restrict__ W2,
                            const float* __restrict__ W3, const float* __restrict__ b3,
                            bf16* __restrict__ Wall, float* __restrict__ b3p) {
    int f = blockIdx.x * 256 + threadIdx.x;
    int lane = f & 63, lm = lane & 15, lq = lane >> 4;
    if (f < W1BASE) {                                // W3^T frags
        int tk = f >> 6, t3 = tk >> 2, kc = tk & 3;
        int col = t3 * 16 + lm;
        bf16x8 pk;
        #pragma unroll
        for (int j = 0; j < 8; ++j) {
            int feat = ((kc * 2 + (j >> 2)) << 4) + (lq << 2) + (j & 3);
            pk[j] = (col < OUTD) ? (bf16)W3[feat * OUTD + col] : (bf16)0.f;
        }
        *(bf16x8*)&Wall[(size_t)f * 8] = pk;
    } else if (f < W2BASE) {                         // W1^T frags (identity k, 7 feats)
        int t = (f - W1BASE) >> 6;
        int m = t * 16 + lm;
        bf16x8 pk;
        #pragma unroll
        for (int j = 0; j < 8; ++j) {
            int k = lq * 8 + j;
            pk[j] = (k < 7) ? (bf16)W1[k * HID + m] : (bf16)0.f;
        }
        *(bf16x8*)&Wall[(size_t)f * 8] = pk;
    } else if (f < NFRAG) {                          // W2^T frags
        int tk = (f - W2BASE) >> 6, t2 = tk >> 2, kc = tk & 3;
        int m = t2 * 16 + lm;
        bf16x8 pk;
        #pragma unroll
        for (int j = 0; j < 8; ++j) {
            int feat = ((kc * 2 + (j >> 2)) << 4) + (lq << 2) + (j & 3);
            pk[j] = (bf16)W2[feat * HID + m];
        }
        *(bf16x8*)&Wall[(size_t)f * 8] = pk;
    } else if (f < NFRAG + 144) {                    // b3 padded to 144
        int i = f - NFRAG;
        b3p[i] = (i < OUTD) ? b3[i] : 0.f;
    }
}

__global__ __launch_bounds__(NT, 2) void nsc_main(
    const float* __restrict__ x, const float* __restrict__ c,
    const bf16* __restrict__ Wall, const float* __restrict__ b1,
    const float* __restrict__ b2, const float* __restrict__ b3p,
    float* __restrict__ out_y, float* __restrict__ out_ld, int N)
{
    __shared__ __align__(16) char smem[SMEM_BYTES];
    bf16*  wlds  = (bf16*)smem;                 // staged weight blob
    f16*   shp16 = (f16*)(smem + 36864);        // [128][SRS], overlays W1s+W2s
    float* shld  = (float*)(smem + 77824);      // [128][3]

    const int tid  = threadIdx.x;
    const int g0   = blockIdx.x * TILE;
    const int lane = tid & 63;
    const int wv   = tid >> 6;        // wave owns samples wv*32 .. wv*32+31
    const int lm   = lane & 15;
    const int lq   = lane >> 4;
    const int sbase = wv * 32;

    // ---- Input loads first (overlap with staging) ----
    float vin[2][8];
    #pragma unroll
    for (int set = 0; set < 2; ++set) {
        int g = g0 + sbase + set * 16 + lm;
        #pragma unroll
        for (int j = 0; j < 8; ++j) vin[set][j] = 0.f;
        if (lq == 0 && g < N) {
            vin[set][0] = x[g * 6 + 3]; vin[set][1] = x[g * 6 + 4];
            vin[set][2] = x[g * 6 + 5];
            vin[set][3] = c[g * 4];     vin[set][4] = c[g * 4 + 1];
            vin[set][5] = c[g * 4 + 2]; vin[set][6] = c[g * 4 + 3];
        }
    }

    // ---- Stage the 77824 B weight blob: 19 x (dwordx4 load + b128 LDS store) ----
    {
        const float4* src = (const float4*)Wall;
        float4* dst = (float4*)smem;
        #pragma unroll
        for (int j = 0; j < 19; ++j) {
            int idx = tid + j * 256;          // 0..4863
            dst[idx] = src[idx];
        }
    }
    __syncthreads();   // staging complete (drains vmcnt+lgkmcnt)

    // ---- Build B1 input fragments (B[k=lq*8+j][n=sample lm]) ----
    bf16x8 inb[2];
    #pragma unroll
    for (int set = 0; set < 2; ++set) {
        bf16x8 t;
        #pragma unroll
        for (int j = 0; j < 8; ++j) t[j] = (bf16)vin[set][j];
        inb[set] = t;
    }

    // ---- Phase 1: h1^T = W1^T @ in^T + b1 ----
    f32x4 acc1[2][8];
    {
        #pragma unroll
        for (int t = 0; t < 8; ++t) {
            f32x4 bb = *(const f32x4*)&b1[t * 16 + lq * 4];
            acc1[0][t] = bb; acc1[1][t] = bb;
        }
        #pragma unroll
        for (int t = 0; t < 8; ++t) {
            bf16x8 wf = *(const bf16x8*)&wlds[(size_t)((W1BASE + t * 64 + lane)) * 8];
            acc1[0][t] = __builtin_amdgcn_mfma_f32_16x16x32_bf16(wf, inb[0], acc1[0][t], 0, 0, 0);
            acc1[1][t] = __builtin_amdgcn_mfma_f32_16x16x32_bf16(wf, inb[1], acc1[1][t], 0, 0, 0);
        }
    }
    // in-lane D->B repack: B2 slot (kc,j) <- relu(D1[t = kc*2+(j>>2)].r[j&3])
    bf16x8 h1B[2][4];
    #pragma unroll
    for (int set = 0; set < 2; ++set)
        #pragma unroll
        for (int kc = 0; kc < 4; ++kc) {
            bf16x8 hb;
            #pragma unroll
            for (int j = 0; j < 8; ++j)
                hb[j] = (bf16)fmaxf(acc1[set][kc * 2 + (j >> 2)][j & 3], 0.f);
            h1B[set][kc] = hb;
        }

    // ---- Phase 2: h2^T = W2^T @ h1^T + b2 ----
    bf16x8 h2B[2][4];
    #pragma unroll
    for (int tp = 0; tp < 4; ++tp) {
        f32x4 acc[2][2];
        #pragma unroll
        for (int dt = 0; dt < 2; ++dt) {
            f32x4 bb = *(const f32x4*)&b2[(tp * 2 + dt) * 16 + lq * 4];
            acc[0][dt] = bb; acc[1][dt] = bb;
        }
        #pragma unroll
        for (int kc = 0; kc < 4; ++kc)
            #pragma unroll
            for (int dt = 0; dt < 2; ++dt) {
                bf16x8 wf = *(const bf16x8*)&wlds[(size_t)((W2BASE + ((tp * 2 + dt) * 4 + kc) * 64 + lane)) * 8];
                acc[0][dt] = __builtin_amdgcn_mfma_f32_16x16x32_bf16(wf, h1B[0][kc], acc[0][dt], 0, 0, 0);
                acc[1][dt] = __builtin_amdgcn_mfma_f32_16x16x32_bf16(wf, h1B[1][kc], acc[1][dt], 0, 0, 0);
            }
        #pragma unroll
        for (int set = 0; set < 2; ++set) {
            bf16x8 hb;
            #pragma unroll
            for (int j = 0; j < 8; ++j)
                hb[j] = (bf16)fmaxf(acc[set][j >> 2][j & 3], 0.f);
            h2B[set][tp] = hb;      // kc-group of next GEMM == tp (f mapping)
        }
    }
    __syncthreads();   // BARRIER A: all waves done reading W1s/W2s -> shp16 free

    // ---- Phase 3: p^T = W3^T @ h2^T + b3 (W3s region: no alias) ----
    #pragma unroll
    for (int t3 = 0; t3 < 9; ++t3) {
        f32x4 acc[2];
        {
            f32x4 bb = *(const f32x4*)&b3p[t3 * 16 + lq * 4];
            acc[0] = bb; acc[1] = bb;
        }
        #pragma unroll
        for (int kc = 0; kc < 4; ++kc) {
            bf16x8 wf = *(const bf16x8*)&wlds[(size_t)((W3BASE + (t3 * 4 + kc) * 64 + lane)) * 8];
            acc[0] = __builtin_amdgcn_mfma_f32_16x16x32_bf16(wf, h2B[0][kc], acc[0], 0, 0, 0);
            acc[1] = __builtin_amdgcn_mfma_f32_16x16x32_bf16(wf, h2B[1][kc], acc[1], 0, 0, 0);
        }
        #pragma unroll
        for (int set = 0; set < 2; ++set) {
            int s = sbase + set * 16 + lm;
            f16x4 pk = (f16x4){(f16)acc[set][0], (f16)acc[set][1],
                               (f16)acc[set][2], (f16)acc[set][3]};
            int off = t3 * 16 + lq * 4;   // off = col; 8B-aligned b64 store
            if (t3 < 8) {
                *(f16x4*)&shp16[s * SRS + off] = pk;
            } else {
                if (lq < 3) *(f16x4*)&shp16[s * SRS + off] = pk;
                else        shp16[s * SRS + 140] = pk[0];   // col 140 only
            }
        }
    }
    __syncthreads();   // BARRIER B: scatters visible to all waves

    // ---- Phase 4: spline; grp mapping keeps d WAVE-UNIFORM ----
    for (int grp = wv; grp < 6; grp += 4) {
        const int d = grp >> 1;
        const int s = ((grp & 1) << 6) + lane;
        const int g = g0 + s;
        if (g < N) {
            const f16* pr = &shp16[s * SRS];
            float w_[16], h_[16], dl[15];
            if (d == 0) {               // p[0..46]
                f16x8 A0 = *(const f16x8*)&pr[0],  A1 = *(const f16x8*)&pr[8];
                f16x8 A2 = *(const f16x8*)&pr[16], A3 = *(const f16x8*)&pr[24];
                f16x8 A4 = *(const f16x8*)&pr[32], A5 = *(const f16x8*)&pr[40];
                #pragma unroll
                for (int i = 0; i < 8; ++i) {
                    w_[i] = (float)A0[i]; w_[8 + i] = (float)A1[i];
                    h_[i] = (float)A2[i]; h_[8 + i] = (float)A3[i];
                    dl[i] = (float)A4[i];
                }
                #pragma unroll
                for (int i = 0; i < 7; ++i) dl[8 + i] = (float)A5[i];
            } else if (d == 1) {        // p[47..93]
                float a47 = (float)pr[47];
                f16x8 A0 = *(const f16x8*)&pr[48], A1 = *(const f16x8*)&pr[56];
                f16x8 A2 = *(const f16x8*)&pr[64], A3 = *(const f16x8*)&pr[72];
                f16x8 A4 = *(const f16x8*)&pr[80], A5 = *(const f16x8*)&pr[88];
                w_[0] = a47;
                #pragma unroll
                for (int i = 0; i < 8; ++i) w_[1 + i] = (float)A0[i];
                #pragma unroll
                for (int i = 0; i < 7; ++i) w_[9 + i] = (float)A1[i];
                h_[0] = (float)A1[7];
                #pragma unroll
                for (int i = 0; i < 8; ++i) h_[1 + i] = (float)A2[i];
                #pragma unroll
                for (int i = 0; i < 7; ++i) h_[9 + i] = (float)A3[i];
                dl[0] = (float)A3[7];
                #pragma unroll
                for (int i = 0; i < 8; ++i) dl[1 + i] = (float)A4[i];
                #pragma unroll
                for (int i = 0; i < 6; ++i) dl[9 + i] = (float)A5[i];
            } else {                    // p[94..140]
                f16x2 B  = *(const f16x2*)&pr[94];
                f16x8 C0 = *(const f16x8*)&pr[96],  C1 = *(const f16x8*)&pr[104];
                f16x8 C2 = *(const f16x8*)&pr[112], C3 = *(const f16x8*)&pr[120];
                f16x8 C4 = *(const f16x8*)&pr[128], E  = *(const f16x8*)&pr[136];
                w_[0] = (float)B[0]; w_[1] = (float)B[1];
                #pragma unroll
                for (int i = 0; i < 8; ++i) w_[2 + i] = (float)C0[i];
                #pragma unroll
                for (int i = 0; i < 6; ++i) w_[10 + i] = (float)C1[i];
                h_[0] = (float)C1[6]; h_[1] = (float)C1[7];
                #pragma unroll
                for (int i = 0; i < 8; ++i) h_[2 + i] = (float)C2[i];
                #pragma unroll
                for (int i = 0; i < 6; ++i) h_[10 + i] = (float)C3[i];
                dl[0] = (float)C3[6]; dl[1] = (float)C3[7];
                #pragma unroll
                for (int i = 0; i < 8; ++i) dl[2 + i] = (float)C4[i];
                #pragma unroll
                for (int i = 0; i < 5; ++i) dl[10 + i] = (float)E[i];
            }

            // softmax without max-subtract: logits are O(1)
            float sw = 0.f, sh = 0.f;
            #pragma unroll
            for (int i = 0; i < 16; ++i) { w_[i] = __expf(w_[i]); sw += w_[i]; }
            #pragma unroll
            for (int i = 0; i < 16; ++i) { h_[i] = __expf(h_[i]); sh += h_[i]; }
            float cwn = 10.f * __builtin_amdgcn_rcpf(sw);
            float chn = 10.f * __builtin_amdgcn_rcpf(sh);
            #pragma unroll
            for (int i = 0; i < 16; ++i) { w_[i] *= cwn; h_[i] *= chn; }

            float xv = x[g * 6 + d];
            bool oob = (xv <= -BND) || (xv >= BND);
            float xm = oob ? -BND : xv;

            // bin scan; softplus deferred to the 2 selected derivs
            float cumx = -BND + w_[0], cumy = -BND + h_[0];
            float xk_b = -BND, yk_b = -BND;
            float wk = w_[0], hk = h_[0];
            float d0l = T1, d1l = dl[0];
            #pragma unroll
            for (int i = 1; i < 16; ++i) {
                bool ge = (xm >= cumx);
                if (ge) {
                    xk_b = cumx; yk_b = cumy;
                    wk = w_[i]; hk = h_[i];
                    d0l = dl[i - 1];
                    d1l = (i < 15) ? dl[i] : T1;
                }
                cumx += w_[i]; cumy += h_[i];
            }
            float d0 = (d0l > 15.f) ? d0l : __logf(1.f + __expf(d0l));
            float d1 = (d1l > 15.f) ? d1l : __logf(1.f + __expf(d1l));

            float rwk = __builtin_amdgcn_rcpf(wk);
            float sk = hk * rwk;
            float relx = (xm - xk_b) * rwk;
            relx = fminf(fmaxf(relx, 0.f), 1.f);
            float r1 = relx * (1.f - relx);
            float den = sk + (d1 + d0 - 2.f * sk) * r1;
            float iden = __builtin_amdgcn_rcpf(den);
            float num = hk * (sk * relx * relx + d0 * r1);
            float y = yk_b + num * iden;
            float omr = 1.f - relx;
            float arg = d1 * relx * relx + 2.f * sk * r1 + d0 * omr * omr;
            float ratio = sk * iden;
            float ld = __logf(ratio * ratio * arg);   // 2log(sk)+log(arg)-2log(den)
            if (oob) { y = xv; ld = 0.f; }

            out_y[g * 6 + d] = y;
            out_y[g * 6 + 3 + d] = x[g * 6 + 3 + d];  // upper pass-through (fp32)
            shld[s * 3 + d] = ld;
        }
    }
    __syncthreads();   // BARRIER C

    // ---- Phase 5: reduce log-det over the 3 dims ----
    if (tid < TILE) {
        int g = g0 + tid;
        if (g < N)
            out_ld[g] = shld[tid * 3] + shld[tid * 3 + 1] + shld[tid * 3 + 2];
    }
}

extern "C" void kernel_launch(void* const* d_in, const int* in_sizes, int n_in,
                              void* d_out, int out_size, void* d_ws, size_t ws_size,
                              hipStream_t stream) {
    const float* x  = (const float*)d_in[0];
    const float* c  = (const float*)d_in[1];
    const float* W1 = (const float*)d_in[2];
    const float* b1 = (const float*)d_in[3];
    const float* W2 = (const float*)d_in[4];
    const float* b2 = (const float*)d_in[5];
    const float* W3 = (const float*)d_in[6];
    const float* b3 = (const float*)d_in[7];

    const int N = in_sizes[0] / 6;              // 500000
    float* out_y  = (float*)d_out;
    float* out_ld = (float*)d_out + (size_t)N * 6;

    bf16*  Wall = (bf16*)d_ws;                          // 77824 B blob
    float* b3p  = (float*)((char*)d_ws + B3P_OFF);      // 576 B

    int nthreads = NFRAG + 144;                 // 5008
    nsc_prepack<<<(nthreads + 255) / 256, 256, 0, stream>>>(W1, W2, W3, b3,
                                                            Wall, b3p);

    int nblocks = (N + TILE - 1) / TILE;        // 3907
    nsc_main<<<nblocks, NT, 0, stream>>>(x, c, Wall, b1, b2, b3p,
                                         out_y, out_ld, N);
}